// Round 7
// baseline (321.001 us; speedup 1.0000x reference)
//
#include <hip/hip_runtime.h>
#include <hip/hip_bf16.h>

typedef unsigned int u32;
typedef unsigned short u16;
typedef __attribute__((ext_vector_type(8))) short short8;
typedef __attribute__((ext_vector_type(4))) float f32x4;

#define N_NODES 100000
#define N_EDGES 1600000
#define N_GRAPHS 1024
#define BUK_SHIFT 7         // 128 nodes per bucket
#define NBUK 782            // ceil(100000 / 128)
#define SCAT_EPT 16         // edges per thread in bucket_scatter
#define SCAT_TILE (256 * SCAT_EPT)

// ---- bf16 helpers (RNE) ----
__device__ __forceinline__ float bflo(u32 u) { return __uint_as_float(u << 16); }
__device__ __forceinline__ float bfhi(u32 u) { return __uint_as_float(u & 0xFFFF0000u); }
__device__ __forceinline__ u32 bf1(float a) {
    u32 ua = __float_as_uint(a);
    ua += 0x7FFF + ((ua >> 16) & 1);
    return ua >> 16;
}
__device__ __forceinline__ u32 bfpack(float a, float b) {
    u32 ua = __float_as_uint(a);
    u32 ub = __float_as_uint(b);
    ua += 0x7FFF + ((ua >> 16) & 1);
    ub += 0x7FFF + ((ub >> 16) & 1);
    return (ua >> 16) | (ub & 0xFFFF0000u);
}
__device__ __forceinline__ void unpack8(uint4 v, float* f) {
    f[0] = bflo(v.x); f[1] = bfhi(v.x); f[2] = bflo(v.y); f[3] = bfhi(v.y);
    f[4] = bflo(v.z); f[5] = bfhi(v.z); f[6] = bflo(v.w); f[7] = bfhi(v.w);
}

// ---------------- bucket histogram (LDS-privatized) ----------------
__global__ __launch_bounds__(256) void bhist_kernel(const int* __restrict__ dst,
                                                    int* __restrict__ bhist, int E) {
    __shared__ int lh[NBUK];
    for (int i = threadIdx.x; i < NBUK; i += 256) lh[i] = 0;
    __syncthreads();
    int i = blockIdx.x * blockDim.x + threadIdx.x;
    int stride = gridDim.x * blockDim.x;
    for (; i < E; i += stride) atomicAdd(&lh[dst[i] >> BUK_SHIFT], 1);
    __syncthreads();
    for (int b = threadIdx.x; b < NBUK; b += 256)
        if (lh[b]) atomicAdd(&bhist[b], lh[b]);
}

// ---------------- exclusive scan of bucket hist (1 block) ----------------
__global__ __launch_bounds__(256) void bscan_kernel(const int* __restrict__ bhist,
                                                    int* __restrict__ boff,
                                                    int* __restrict__ bcursor) {
    __shared__ int lds[256];
    int tid = threadIdx.x;
    int i0 = tid * 4;
    int e[4];
#pragma unroll
    for (int k = 0; k < 4; ++k) e[k] = (i0 + k < NBUK) ? bhist[i0 + k] : 0;
    int ts = e[0] + e[1] + e[2] + e[3];
    lds[tid] = ts;
    __syncthreads();
    for (int off = 1; off < 256; off <<= 1) {
        int v = (tid >= off) ? lds[tid - off] : 0;
        __syncthreads();
        lds[tid] += v;
        __syncthreads();
    }
    int run = lds[tid] - ts;  // exclusive
#pragma unroll
    for (int k = 0; k < 4; ++k) {
        if (i0 + k < NBUK) { boff[i0 + k] = run; bcursor[i0 + k] = run; }
        run += e[k];
    }
    if (tid == 255) boff[NBUK] = lds[255];
}

// ---------------- scatter edges into bucket-sorted order (packed) ----------------
__global__ __launch_bounds__(256) void bucket_scatter_kernel(const int* __restrict__ src,
                                                             const int* __restrict__ dst,
                                                             int* __restrict__ bcursor,
                                                             int* __restrict__ sorted, int E) {
    __shared__ int lhist[NBUK];
    __shared__ int lbase[NBUK];
    for (int i = threadIdx.x; i < NBUK; i += 256) lhist[i] = 0;
    __syncthreads();
    int base_i = blockIdx.x * SCAT_TILE;
    int s[SCAT_EPT], d[SCAT_EPT], lp[SCAT_EPT];
#pragma unroll
    for (int k = 0; k < SCAT_EPT; ++k) {
        int i = base_i + k * 256 + threadIdx.x;
        if (i < E) {
            s[k] = src[i];
            d[k] = dst[i];
            lp[k] = atomicAdd(&lhist[d[k] >> BUK_SHIFT], 1);
        }
    }
    __syncthreads();
    for (int b = threadIdx.x; b < NBUK; b += 256) {
        int c = lhist[b];
        lbase[b] = c ? atomicAdd(&bcursor[b], c) : 0;
    }
    __syncthreads();
#pragma unroll
    for (int k = 0; k < SCAT_EPT; ++k) {
        int i = base_i + k * 256 + threadIdx.x;
        if (i < E) {
            int b = d[k] >> BUK_SHIFT;
            sorted[lbase[b] + lp[k]] = (s[k] << BUK_SHIFT) | (d[k] & 127);
        }
    }
}

// ---------------- fused: per-bucket count + dinv + rowptr + CSR fill ----------------
__global__ __launch_bounds__(256) void bucket_build_kernel(const int* __restrict__ sorted,
                                                           const int* __restrict__ boff,
                                                           int* __restrict__ rowptr,
                                                           float* __restrict__ dinv,
                                                           int* __restrict__ esrc, int n) {
    __shared__ int ncnt[128];
    __shared__ int sc[128];
    __shared__ int lbase[128];
    __shared__ int lcur[128];
    int tid = threadIdx.x;
    int b = blockIdx.x;
    int start = boff[b], end = boff[b + 1];
    if (tid < 128) ncnt[tid] = 0;
    __syncthreads();
    for (int j = start + tid; j < end; j += 256)
        atomicAdd(&ncnt[sorted[j] & 127], 1);
    __syncthreads();
    if (tid < 128) sc[tid] = ncnt[tid];
    __syncthreads();
    for (int off = 1; off < 128; off <<= 1) {
        int v = 0;
        if (tid < 128 && tid >= off) v = sc[tid - off];
        __syncthreads();
        if (tid < 128) sc[tid] += v;
        __syncthreads();
    }
    if (tid < 128) {
        int excl = sc[tid] - ncnt[tid];
        lbase[tid] = start + excl;
        lcur[tid] = 0;
        int node = (b << BUK_SHIFT) + tid;
        if (node < n) {
            rowptr[node] = start + excl;
            dinv[node] = rsqrtf((float)ncnt[tid] + 1.0f);
        }
        if (node == n - 1) rowptr[n] = end;
    }
    __syncthreads();
    for (int j = start + tid; j < end; j += 256) {
        int p = sorted[j];
        int ln = p & 127;
        int off = atomicAdd(&lcur[ln], 1);
        esrc[lbase[ln] + off] = p >> BUK_SHIFT;
    }
}

// ---------------- W transpose + f32->bf16: Wt[n][k] = bf16(W[k][n]) ----------------
__global__ void convw_kernel(const float* __restrict__ W, u16* __restrict__ Wt,
                             int K, int Nout) {
    int i = blockIdx.x * 256 + threadIdx.x;
    if (i < K * Nout) {
        int n = i / K, k = i % K;
        Wt[i] = (u16)bf1(W[(size_t)k * Nout + n]);
    }
}

// ---------------- MFMA GEMM: C[M][NOUT] bf16 = A[M][K] @ Wt^T ----------------
// A_F32=1: A is f32, rows scaled by dinv on load (A := dinv[r]*A[r])
// EPI=0:   C = A@W (pack bf16)
// EPI=1:   C = bf16( dinv[r] * relu(A@W + bias) )
template <int K, int NOUT, int EPI, int A_F32>
__global__ __launch_bounds__(256) void mfma_gemm_kernel(const void* __restrict__ Aptr,
                                                        const u16* __restrict__ Wt,
                                                        const float* __restrict__ bias,
                                                        const float* __restrict__ dinv,
                                                        u16* __restrict__ C, int M) {
    constexpr int KP = K + 8;         // padded LDS row (bf16 elems)
    constexpr int NK = K / 32;        // mfma k-steps
    constexpr int NCT = NOUT / 16;    // col tiles
    __shared__ u16 wlds[NOUT * KP];
    int tid = threadIdx.x;
    constexpr int TOT = NOUT * K / 8; // uint4 elements of Wt
    const uint4* wt4 = (const uint4*)Wt;
    for (int i = tid; i < TOT; i += 256) {
        int r = i / (K / 8), kc = i % (K / 8);
        *(uint4*)&wlds[r * KP + kc * 8] = wt4[i];
    }
    __syncthreads();

    int lane = tid & 63;
    int w = tid >> 6;
    int row0 = blockIdx.x * 256 + w * 64;

    short8 afr[4][NK];
#pragma unroll
    for (int sub = 0; sub < 4; ++sub) {
        int arow = row0 + sub * 16 + (lane & 15);
        arow = min(arow, M - 1);
        if (A_F32) {
            const float* Af = (const float*)Aptr;
            float dv = dinv[arow];
#pragma unroll
            for (int ks = 0; ks < NK; ++ks) {
                int k0 = ks * 32 + (lane >> 4) * 8;
                const float4* p = (const float4*)(Af + (size_t)arow * K + k0);
                float4 uu = p[0], vv = p[1];
                uint4 q;
                q.x = bfpack(dv * uu.x, dv * uu.y);
                q.y = bfpack(dv * uu.z, dv * uu.w);
                q.z = bfpack(dv * vv.x, dv * vv.y);
                q.w = bfpack(dv * vv.z, dv * vv.w);
                afr[sub][ks] = *(short8*)&q;
            }
        } else {
            const u16* Ab = (const u16*)Aptr;
#pragma unroll
            for (int ks = 0; ks < NK; ++ks) {
                int k0 = ks * 32 + (lane >> 4) * 8;
                afr[sub][ks] = *(const short8*)(Ab + (size_t)arow * K + k0);
            }
        }
    }

    for (int ct = 0; ct < NCT; ++ct) {
        int bcol = ct * 16 + (lane & 15);
        short8 bfr[NK];
#pragma unroll
        for (int ks = 0; ks < NK; ++ks) {
            int k0 = ks * 32 + (lane >> 4) * 8;
            bfr[ks] = *(const short8*)&wlds[bcol * KP + k0];
        }
        float bc = 0.0f;
        if (EPI == 1) bc = bias[bcol];
#pragma unroll
        for (int sub = 0; sub < 4; ++sub) {
            f32x4 acc = {0.0f, 0.0f, 0.0f, 0.0f};
#pragma unroll
            for (int ks = 0; ks < NK; ++ks)
                acc = __builtin_amdgcn_mfma_f32_16x16x32_bf16(afr[sub][ks], bfr[ks], acc,
                                                              0, 0, 0);
            int rbase = row0 + sub * 16 + (lane >> 4) * 4;
            if (rbase < M) {
                if (EPI == 0) {
#pragma unroll
                    for (int j = 0; j < 4; ++j)
                        C[(size_t)(rbase + j) * NOUT + bcol] = (u16)bf1(acc[j]);
                } else {
                    float4 dv4 = *(const float4*)(dinv + rbase);
                    float dvv[4] = {dv4.x, dv4.y, dv4.z, dv4.w};
#pragma unroll
                    for (int j = 0; j < 4; ++j) {
                        float o = dvv[j] * fmaxf(acc[j] + bc, 0.0f);
                        C[(size_t)(rbase + j) * NOUT + bcol] = (u16)bf1(o);
                    }
                }
            }
        }
    }
}

// ---- edge-parallel wave aggregation: one 64-lane wave per node ----
// EPG = 64/TPN edge groups walk strided slices of the node's edge list
// (4-8 independent gather chains in flight), then cross-group shfl_xor reduce.
// EPI=0: out = relu(dv*acc + bias)          (agg3, f32 out)
// EPI=1: out = dv * relu(dv*acc + bias)     (agg1 -> pre-scaled h1')
// EPI=2: out = dv * acc                     (pre-agg2 on pre-scaled h1')
template <int F, int OUT_BF, int EPI>
__global__ __launch_bounds__(256) void pull_agg_w_kernel(const uint4* __restrict__ TS,
                                                         const int* __restrict__ rowptr,
                                                         const int* __restrict__ esrc,
                                                         const float* __restrict__ dinv,
                                                         const float* __restrict__ bias,
                                                         void* __restrict__ OUT, int n) {
    constexpr int TPN = F / 8;          // lanes per feature-row (8 or 16)
    constexpr int EPG = 64 / TPN;       // edge groups per wave (8 or 4)
    int wid = threadIdx.x >> 6;
    int lane = threadIdx.x & 63;
    int node = blockIdx.x * 4 + wid;
    if (node >= n) return;              // wave-uniform
    int t = lane % TPN;
    int g = lane / TPN;
    float acc[8] = {0, 0, 0, 0, 0, 0, 0, 0};
    float f[8];
    int jb = rowptr[node], je = rowptr[node + 1];
    for (int j = jb + g; j < je; j += EPG) {
        int s = esrc[j];
        unpack8(TS[(size_t)s * TPN + t], f);
#pragma unroll
        for (int k = 0; k < 8; ++k) acc[k] += f[k];
    }
    // reduce partial sums across edge groups (lanes differing in bits >= log2(TPN))
#pragma unroll
    for (int k = 0; k < 8; ++k) {
#pragma unroll
        for (int m = TPN; m < 64; m <<= 1) acc[k] += __shfl_xor(acc[k], m, 64);
    }
    if (g == 0) {
        unpack8(TS[(size_t)node * TPN + t], f);   // self-loop term
#pragma unroll
        for (int k = 0; k < 8; ++k) acc[k] += f[k];
        float dv = dinv[node];
        float o[8];
        if (EPI == 2) {
#pragma unroll
            for (int k = 0; k < 8; ++k) o[k] = dv * acc[k];
        } else {
            const float4* bias4 = (const float4*)bias;
            float4 b0 = bias4[t * 2], b1v = bias4[t * 2 + 1];
            float bb[8] = {b0.x, b0.y, b0.z, b0.w, b1v.x, b1v.y, b1v.z, b1v.w};
#pragma unroll
            for (int k = 0; k < 8; ++k) o[k] = fmaxf(dv * acc[k] + bb[k], 0.0f);
            if (EPI == 1) {
#pragma unroll
                for (int k = 0; k < 8; ++k) o[k] *= dv;
            }
        }
        if (OUT_BF) {
            uint4 pv;
            pv.x = bfpack(o[0], o[1]); pv.y = bfpack(o[2], o[3]);
            pv.z = bfpack(o[4], o[5]); pv.w = bfpack(o[6], o[7]);
            ((uint4*)OUT)[(size_t)node * TPN + t] = pv;
        } else {
            float4* O4 = (float4*)OUT;
            O4[(size_t)node * (F / 4) + t * 2] = make_float4(o[0], o[1], o[2], o[3]);
            O4[(size_t)node * (F / 4) + t * 2 + 1] = make_float4(o[4], o[5], o[6], o[7]);
        }
    }
}

// ---------------- mean-pool (batch sorted -> binary search range) + FC ----------------
__global__ __launch_bounds__(128) void pool_fc_kernel(const float* __restrict__ H,
                                                      const int* __restrict__ batch,
                                                      const float* __restrict__ Wfc,
                                                      const float* __restrict__ bfc,
                                                      float* __restrict__ OUT, int n) {
    int g = blockIdx.x;
    __shared__ int se[2];
    __shared__ float pooled[128];
    if (threadIdx.x < 2) {
        int target = g + threadIdx.x;
        int lo = 0, hi = n;
        while (lo < hi) {
            int mid = (lo + hi) >> 1;
            if (batch[mid] < target) lo = mid + 1; else hi = mid;
        }
        se[threadIdx.x] = lo;
    }
    __syncthreads();
    int start = se[0], end = se[1];
    float s = 0.0f;
    for (int i = start; i < end; ++i) s += H[(size_t)i * 128 + threadIdx.x];
    float cntf = (float)max(end - start, 1);
    pooled[threadIdx.x] = s / cntf;
    __syncthreads();
    if (threadIdx.x < 10) {
        float o = bfc[threadIdx.x];
        for (int k = 0; k < 128; ++k) o += pooled[k] * Wfc[k * 10 + threadIdx.x];
        OUT[g * 10 + threadIdx.x] = o;
    }
}

extern "C" void kernel_launch(void* const* d_in, const int* in_sizes, int n_in,
                              void* d_out, int out_size, void* d_ws, size_t ws_size,
                              hipStream_t stream) {
    const int N = N_NODES, E = N_EDGES, G = N_GRAPHS;
    const float* x = (const float*)d_in[0];
    const int* ei = (const int*)d_in[1];
    const int* batch = (const int*)d_in[2];
    const float* W1 = (const float*)d_in[3];
    const float* b1 = (const float*)d_in[4];
    const float* W2 = (const float*)d_in[5];
    const float* b2 = (const float*)d_in[6];
    const float* W3 = (const float*)d_in[7];
    const float* b3 = (const float*)d_in[8];
    const float* Wfc = (const float*)d_in[9];
    const float* bfc = (const float*)d_in[10];
    const int* src = ei;
    const int* dst = ei + E;

    char* ws = (char*)d_ws;
    size_t off = 0;
    auto alloc = [&](size_t bytes) {
        void* p = ws + off;
        off = (off + bytes + 255) & ~(size_t)255;
        return p;
    };
    float* dinv = (float*)alloc((size_t)N * 4);
    int* rowptr = (int*)alloc((size_t)(N + 1) * 4);
    int* bhist = (int*)alloc((size_t)NBUK * 4);
    int* boff = (int*)alloc((size_t)(NBUK + 1) * 4);
    int* bcursor = (int*)alloc((size_t)NBUK * 4);
    int* esrc = (int*)alloc((size_t)E * 4);
    u16* W1t = (u16*)alloc((size_t)64 * 128 * 2);    // [64][128]
    u16* W2t = (u16*)alloc((size_t)128 * 64 * 2);    // [128][64]
    u16* W3t = (u16*)alloc((size_t)128 * 128 * 2);   // [128][128]
    u16* TS1 = (u16*)alloc((size_t)N * 64 * 2);      // bf16 [N][64]
    u16* H1S = (u16*)alloc((size_t)N * 64 * 2);      // bf16 [N][64], pre-scaled by dinv
    u16* G2 = (u16*)alloc((size_t)N * 64 * 2);       // bf16 [N][64]
    u16* H2S = (u16*)alloc((size_t)N * 128 * 2);     // bf16 [N][128], pre-scaled by dinv
    u16* TS3 = (u16*)alloc((size_t)N * 128 * 2);     // bf16 [N][128]
    float* H3 = (float*)alloc((size_t)N * 128 * 4);  // f32 [N][128]
    int* sorted = (int*)TS3;  // packed edges during preproc; TS3 written later

    // ---- graph preprocessing: bucket-sorted CSR build ----
    hipMemsetAsync(bhist, 0, (size_t)NBUK * 4, stream);
    bhist_kernel<<<128, 256, 0, stream>>>(dst, bhist, E);
    bscan_kernel<<<1, 256, 0, stream>>>(bhist, boff, bcursor);
    const int NTILES = (E + SCAT_TILE - 1) / SCAT_TILE;
    bucket_scatter_kernel<<<NTILES, 256, 0, stream>>>(src, dst, bcursor, sorted, E);
    bucket_build_kernel<<<NBUK, 256, 0, stream>>>(sorted, boff, rowptr, dinv, esrc, N);

    // ---- weight conversion (transposed bf16) ----
    convw_kernel<<<32, 256, 0, stream>>>(W1, W1t, 128, 64);
    convw_kernel<<<32, 256, 0, stream>>>(W2, W2t, 64, 128);
    convw_kernel<<<64, 256, 0, stream>>>(W3, W3t, 128, 128);

    const int GEMM_GRID = (N + 255) / 256;
    const int AGG_GRID = (N + 3) / 4;   // one wave per node, 4 waves/block
    // ---- layer 1: 128 -> 64 : ts1 = (dinv*x) @ W1 ; h1' = dinv*relu(dinv*gather + b1) ----
    mfma_gemm_kernel<128, 64, 0, 1><<<GEMM_GRID, 256, 0, stream>>>(x, W1t, nullptr, dinv,
                                                                   TS1, N);
    pull_agg_w_kernel<64, 1, 1><<<AGG_GRID, 256, 0, stream>>>((const uint4*)TS1, rowptr,
                                                              esrc, dinv, b1, H1S, N);
    // ---- layer 2: 64 -> 128 : g2 = dinv*(gather(h1')+h1'); h2s = dinv*relu(g2@W2+b2) ----
    pull_agg_w_kernel<64, 1, 2><<<AGG_GRID, 256, 0, stream>>>((const uint4*)H1S, rowptr,
                                                              esrc, dinv, nullptr, G2, N);
    mfma_gemm_kernel<64, 128, 1, 0><<<GEMM_GRID, 256, 0, stream>>>(G2, W2t, b2, dinv,
                                                                   H2S, N);
    // ---- layer 3: 128 -> 128 : ts3 = h2s @ W3 ; h3 = relu(dinv*gather + b3) ----
    mfma_gemm_kernel<128, 128, 0, 0><<<GEMM_GRID, 256, 0, stream>>>(H2S, W3t, nullptr, dinv,
                                                                    TS3, N);
    pull_agg_w_kernel<128, 0, 0><<<AGG_GRID, 256, 0, stream>>>((const uint4*)TS3, rowptr,
                                                               esrc, dinv, b3, H3, N);
    // ---- mean pool + FC ----
    pool_fc_kernel<<<G, 128, 0, stream>>>(H3, batch, Wfc, bfc, (float*)d_out, N);
}

// Round 8
// 298.170 us; speedup vs baseline: 1.0766x; 1.0766x over previous
//
#include <hip/hip_runtime.h>
#include <hip/hip_bf16.h>

typedef unsigned int u32;
typedef unsigned short u16;
typedef __attribute__((ext_vector_type(8))) short short8;
typedef __attribute__((ext_vector_type(4))) float f32x4;

#define N_NODES 100000
#define N_EDGES 1600000
#define N_GRAPHS 1024
#define BUK_SHIFT 7         // 128 nodes per bucket
#define NBUK 782            // ceil(100000 / 128)
#define SCAT_EPT 16         // edges per thread in bucket_scatter
#define SCAT_TILE (256 * SCAT_EPT)

// ---- bf16 helpers (RNE) ----
__device__ __forceinline__ float bflo(u32 u) { return __uint_as_float(u << 16); }
__device__ __forceinline__ float bfhi(u32 u) { return __uint_as_float(u & 0xFFFF0000u); }
__device__ __forceinline__ u32 bf1(float a) {
    u32 ua = __float_as_uint(a);
    ua += 0x7FFF + ((ua >> 16) & 1);
    return ua >> 16;
}
__device__ __forceinline__ u32 bfpack(float a, float b) {
    u32 ua = __float_as_uint(a);
    u32 ub = __float_as_uint(b);
    ua += 0x7FFF + ((ua >> 16) & 1);
    ub += 0x7FFF + ((ub >> 16) & 1);
    return (ua >> 16) | (ub & 0xFFFF0000u);
}
__device__ __forceinline__ void unpack8(uint4 v, float* f) {
    f[0] = bflo(v.x); f[1] = bfhi(v.x); f[2] = bflo(v.y); f[3] = bfhi(v.y);
    f[4] = bflo(v.z); f[5] = bfhi(v.z); f[6] = bflo(v.w); f[7] = bfhi(v.w);
}

// ---------------- bucket histogram (LDS-privatized) ----------------
__global__ __launch_bounds__(256) void bhist_kernel(const int* __restrict__ dst,
                                                    int* __restrict__ bhist, int E) {
    __shared__ int lh[NBUK];
    for (int i = threadIdx.x; i < NBUK; i += 256) lh[i] = 0;
    __syncthreads();
    int i = blockIdx.x * blockDim.x + threadIdx.x;
    int stride = gridDim.x * blockDim.x;
    for (; i < E; i += stride) atomicAdd(&lh[dst[i] >> BUK_SHIFT], 1);
    __syncthreads();
    for (int b = threadIdx.x; b < NBUK; b += 256)
        if (lh[b]) atomicAdd(&bhist[b], lh[b]);
}

// ---------------- exclusive scan of bucket hist (1 block) ----------------
__global__ __launch_bounds__(256) void bscan_kernel(const int* __restrict__ bhist,
                                                    int* __restrict__ boff,
                                                    int* __restrict__ bcursor) {
    __shared__ int lds[256];
    int tid = threadIdx.x;
    int i0 = tid * 4;
    int e[4];
#pragma unroll
    for (int k = 0; k < 4; ++k) e[k] = (i0 + k < NBUK) ? bhist[i0 + k] : 0;
    int ts = e[0] + e[1] + e[2] + e[3];
    lds[tid] = ts;
    __syncthreads();
    for (int off = 1; off < 256; off <<= 1) {
        int v = (tid >= off) ? lds[tid - off] : 0;
        __syncthreads();
        lds[tid] += v;
        __syncthreads();
    }
    int run = lds[tid] - ts;  // exclusive
#pragma unroll
    for (int k = 0; k < 4; ++k) {
        if (i0 + k < NBUK) { boff[i0 + k] = run; bcursor[i0 + k] = run; }
        run += e[k];
    }
    if (tid == 255) boff[NBUK] = lds[255];
}

// ---------------- scatter edges into bucket-sorted order (packed) ----------------
__global__ __launch_bounds__(256) void bucket_scatter_kernel(const int* __restrict__ src,
                                                             const int* __restrict__ dst,
                                                             int* __restrict__ bcursor,
                                                             int* __restrict__ sorted, int E) {
    __shared__ int lhist[NBUK];
    __shared__ int lbase[NBUK];
    for (int i = threadIdx.x; i < NBUK; i += 256) lhist[i] = 0;
    __syncthreads();
    int base_i = blockIdx.x * SCAT_TILE;
    int s[SCAT_EPT], d[SCAT_EPT], lp[SCAT_EPT];
#pragma unroll
    for (int k = 0; k < SCAT_EPT; ++k) {
        int i = base_i + k * 256 + threadIdx.x;
        if (i < E) {
            s[k] = src[i];
            d[k] = dst[i];
            lp[k] = atomicAdd(&lhist[d[k] >> BUK_SHIFT], 1);
        }
    }
    __syncthreads();
    for (int b = threadIdx.x; b < NBUK; b += 256) {
        int c = lhist[b];
        lbase[b] = c ? atomicAdd(&bcursor[b], c) : 0;
    }
    __syncthreads();
#pragma unroll
    for (int k = 0; k < SCAT_EPT; ++k) {
        int i = base_i + k * 256 + threadIdx.x;
        if (i < E) {
            int b = d[k] >> BUK_SHIFT;
            sorted[lbase[b] + lp[k]] = (s[k] << BUK_SHIFT) | (d[k] & 127);
        }
    }
}

// ---------------- fused: per-bucket count + dinv + rowptr + CSR fill ----------------
__global__ __launch_bounds__(256) void bucket_build_kernel(const int* __restrict__ sorted,
                                                           const int* __restrict__ boff,
                                                           int* __restrict__ rowptr,
                                                           float* __restrict__ dinv,
                                                           int* __restrict__ esrc, int n) {
    __shared__ int ncnt[128];
    __shared__ int sc[128];
    __shared__ int lbase[128];
    __shared__ int lcur[128];
    int tid = threadIdx.x;
    int b = blockIdx.x;
    int start = boff[b], end = boff[b + 1];
    if (tid < 128) ncnt[tid] = 0;
    __syncthreads();
    for (int j = start + tid; j < end; j += 256)
        atomicAdd(&ncnt[sorted[j] & 127], 1);
    __syncthreads();
    if (tid < 128) sc[tid] = ncnt[tid];
    __syncthreads();
    for (int off = 1; off < 128; off <<= 1) {
        int v = 0;
        if (tid < 128 && tid >= off) v = sc[tid - off];
        __syncthreads();
        if (tid < 128) sc[tid] += v;
        __syncthreads();
    }
    if (tid < 128) {
        int excl = sc[tid] - ncnt[tid];
        lbase[tid] = start + excl;
        lcur[tid] = 0;
        int node = (b << BUK_SHIFT) + tid;
        if (node < n) {
            rowptr[node] = start + excl;
            dinv[node] = rsqrtf((float)ncnt[tid] + 1.0f);
        }
        if (node == n - 1) rowptr[n] = end;
    }
    __syncthreads();
    for (int j = start + tid; j < end; j += 256) {
        int p = sorted[j];
        int ln = p & 127;
        int off = atomicAdd(&lcur[ln], 1);
        esrc[lbase[ln] + off] = p >> BUK_SHIFT;
    }
}

// ---------------- all three W transposes + f32->bf16 in one kernel ----------------
__global__ __launch_bounds__(256) void convw_all_kernel(const float* __restrict__ W1,
                                                        const float* __restrict__ W2,
                                                        const float* __restrict__ W3,
                                                        u16* __restrict__ W1t,
                                                        u16* __restrict__ W2t,
                                                        u16* __restrict__ W3t) {
    int i = blockIdx.x * 256 + threadIdx.x;   // total 32768
    if (i < 8192) {                 // W1: [128][64] -> W1t [64][128]
        int n = i / 128, k = i % 128;
        W1t[i] = (u16)bf1(W1[(size_t)k * 64 + n]);
    } else if (i < 16384) {         // W2: [64][128] -> W2t [128][64]
        int j = i - 8192;
        int n = j / 64, k = j % 64;
        W2t[j] = (u16)bf1(W2[(size_t)k * 128 + n]);
    } else if (i < 32768) {         // W3: [128][128] -> W3t [128][128]
        int j = i - 16384;
        int n = j / 128, k = j % 128;
        W3t[j] = (u16)bf1(W3[(size_t)k * 128 + n]);
    }
}

// ---------------- MFMA GEMM: C[M][NOUT] bf16 = A[M][K] @ Wt^T ----------------
template <int K, int NOUT, int EPI, int A_F32>
__global__ __launch_bounds__(256) void mfma_gemm_kernel(const void* __restrict__ Aptr,
                                                        const u16* __restrict__ Wt,
                                                        const float* __restrict__ bias,
                                                        const float* __restrict__ dinv,
                                                        u16* __restrict__ C, int M) {
    constexpr int KP = K + 8;
    constexpr int NK = K / 32;
    constexpr int NCT = NOUT / 16;
    __shared__ u16 wlds[NOUT * KP];
    int tid = threadIdx.x;
    constexpr int TOT = NOUT * K / 8;
    const uint4* wt4 = (const uint4*)Wt;
    for (int i = tid; i < TOT; i += 256) {
        int r = i / (K / 8), kc = i % (K / 8);
        *(uint4*)&wlds[r * KP + kc * 8] = wt4[i];
    }
    __syncthreads();

    int lane = tid & 63;
    int w = tid >> 6;
    int row0 = blockIdx.x * 256 + w * 64;

    short8 afr[4][NK];
#pragma unroll
    for (int sub = 0; sub < 4; ++sub) {
        int arow = row0 + sub * 16 + (lane & 15);
        arow = min(arow, M - 1);
        if (A_F32) {
            const float* Af = (const float*)Aptr;
            float dv = dinv[arow];
#pragma unroll
            for (int ks = 0; ks < NK; ++ks) {
                int k0 = ks * 32 + (lane >> 4) * 8;
                const float4* p = (const float4*)(Af + (size_t)arow * K + k0);
                float4 uu = p[0], vv = p[1];
                uint4 q;
                q.x = bfpack(dv * uu.x, dv * uu.y);
                q.y = bfpack(dv * uu.z, dv * uu.w);
                q.z = bfpack(dv * vv.x, dv * vv.y);
                q.w = bfpack(dv * vv.z, dv * vv.w);
                afr[sub][ks] = *(short8*)&q;
            }
        } else {
            const u16* Ab = (const u16*)Aptr;
#pragma unroll
            for (int ks = 0; ks < NK; ++ks) {
                int k0 = ks * 32 + (lane >> 4) * 8;
                afr[sub][ks] = *(const short8*)(Ab + (size_t)arow * K + k0);
            }
        }
    }

    for (int ct = 0; ct < NCT; ++ct) {
        int bcol = ct * 16 + (lane & 15);
        short8 bfr[NK];
#pragma unroll
        for (int ks = 0; ks < NK; ++ks) {
            int k0 = ks * 32 + (lane >> 4) * 8;
            bfr[ks] = *(const short8*)&wlds[bcol * KP + k0];
        }
        float bc = 0.0f;
        if (EPI == 1) bc = bias[bcol];
#pragma unroll
        for (int sub = 0; sub < 4; ++sub) {
            f32x4 acc = {0.0f, 0.0f, 0.0f, 0.0f};
#pragma unroll
            for (int ks = 0; ks < NK; ++ks)
                acc = __builtin_amdgcn_mfma_f32_16x16x32_bf16(afr[sub][ks], bfr[ks], acc,
                                                              0, 0, 0);
            int rbase = row0 + sub * 16 + (lane >> 4) * 4;
            if (rbase < M) {
                if (EPI == 0) {
#pragma unroll
                    for (int j = 0; j < 4; ++j)
                        C[(size_t)(rbase + j) * NOUT + bcol] = (u16)bf1(acc[j]);
                } else {
                    float4 dv4 = *(const float4*)(dinv + rbase);
                    float dvv[4] = {dv4.x, dv4.y, dv4.z, dv4.w};
#pragma unroll
                    for (int j = 0; j < 4; ++j) {
                        float o = dvv[j] * fmaxf(acc[j] + bc, 0.0f);
                        C[(size_t)(rbase + j) * NOUT + bcol] = (u16)bf1(o);
                    }
                }
            }
        }
    }
}

// ---- edge-parallel wave aggregation (F=64 layers) ----
// EPI=1: out = dv * relu(dv*acc + bias)     (agg1 -> pre-scaled h1')
// EPI=2: out = dv * acc                     (pre-agg2 on pre-scaled h1')
template <int F, int OUT_BF, int EPI>
__global__ __launch_bounds__(256) void pull_agg_w_kernel(const uint4* __restrict__ TS,
                                                         const int* __restrict__ rowptr,
                                                         const int* __restrict__ esrc,
                                                         const float* __restrict__ dinv,
                                                         const float* __restrict__ bias,
                                                         void* __restrict__ OUT, int n) {
    constexpr int TPN = F / 8;
    constexpr int EPG = 64 / TPN;
    int wid = threadIdx.x >> 6;
    int lane = threadIdx.x & 63;
    int node = blockIdx.x * 4 + wid;
    if (node >= n) return;
    int t = lane % TPN;
    int g = lane / TPN;
    float acc[8] = {0, 0, 0, 0, 0, 0, 0, 0};
    float f[8];
    int jb = rowptr[node], je = rowptr[node + 1];
    for (int j = jb + g; j < je; j += EPG) {
        int s = esrc[j];
        unpack8(TS[(size_t)s * TPN + t], f);
#pragma unroll
        for (int k = 0; k < 8; ++k) acc[k] += f[k];
    }
#pragma unroll
    for (int k = 0; k < 8; ++k) {
#pragma unroll
        for (int m = TPN; m < 64; m <<= 1) acc[k] += __shfl_xor(acc[k], m, 64);
    }
    if (g == 0) {
        unpack8(TS[(size_t)node * TPN + t], f);
#pragma unroll
        for (int k = 0; k < 8; ++k) acc[k] += f[k];
        float dv = dinv[node];
        float o[8];
        if (EPI == 2) {
#pragma unroll
            for (int k = 0; k < 8; ++k) o[k] = dv * acc[k];
        } else {
            const float4* bias4 = (const float4*)bias;
            float4 b0 = bias4[t * 2], b1v = bias4[t * 2 + 1];
            float bb[8] = {b0.x, b0.y, b0.z, b0.w, b1v.x, b1v.y, b1v.z, b1v.w};
#pragma unroll
            for (int k = 0; k < 8; ++k) o[k] = fmaxf(dv * acc[k] + bb[k], 0.0f);
            if (EPI == 1) {
#pragma unroll
                for (int k = 0; k < 8; ++k) o[k] *= dv;
            }
        }
        if (OUT_BF) {
            uint4 pv;
            pv.x = bfpack(o[0], o[1]); pv.y = bfpack(o[2], o[3]);
            pv.z = bfpack(o[4], o[5]); pv.w = bfpack(o[6], o[7]);
            ((uint4*)OUT)[(size_t)node * TPN + t] = pv;
        } else {
            float4* O4 = (float4*)OUT;
            O4[(size_t)node * (F / 4) + t * 2] = make_float4(o[0], o[1], o[2], o[3]);
            O4[(size_t)node * (F / 4) + t * 2 + 1] = make_float4(o[4], o[5], o[6], o[7]);
        }
    }
}

// ---- fused layer-3 aggregation + mean-pool partial sums ----
// 8 waves/block, one node per wave (grid = n/8 EXACT, no early returns).
// h3 = relu(dv*(sum ts3[src] + ts3[node]) + b3) computed in-register, staged
// in LDS, then run-length reduced by (sorted) graph id -> atomicAdd pooledSums.
__global__ __launch_bounds__(512) void pull_agg_pool_kernel(const uint4* __restrict__ TS,
                                                            const int* __restrict__ rowptr,
                                                            const int* __restrict__ esrc,
                                                            const float* __restrict__ dinv,
                                                            const float* __restrict__ bias,
                                                            const int* __restrict__ batch,
                                                            float* __restrict__ PS, int n) {
    constexpr int TPN = 16;   // F=128: 16 lanes x 8 feats
    constexpr int EPG = 4;
    __shared__ float hrow[8][128];
    __shared__ int ib[8];
    int wid = threadIdx.x >> 6;
    int lane = threadIdx.x & 63;
    int node = blockIdx.x * 8 + wid;
    int t = lane % TPN;
    int g = lane / TPN;
    float acc[8] = {0, 0, 0, 0, 0, 0, 0, 0};
    float f[8];
    int jb = rowptr[node], je = rowptr[node + 1];
    for (int j = jb + g; j < je; j += EPG) {
        int s = esrc[j];
        unpack8(TS[(size_t)s * TPN + t], f);
#pragma unroll
        for (int k = 0; k < 8; ++k) acc[k] += f[k];
    }
#pragma unroll
    for (int k = 0; k < 8; ++k) {
#pragma unroll
        for (int m = TPN; m < 64; m <<= 1) acc[k] += __shfl_xor(acc[k], m, 64);
    }
    if (g == 0) {
        unpack8(TS[(size_t)node * TPN + t], f);
        float dv = dinv[node];
        const float4* bias4 = (const float4*)bias;
        float4 b0 = bias4[t * 2], b1v = bias4[t * 2 + 1];
        float bb[8] = {b0.x, b0.y, b0.z, b0.w, b1v.x, b1v.y, b1v.z, b1v.w};
#pragma unroll
        for (int k = 0; k < 8; ++k)
            hrow[wid][t * 8 + k] = fmaxf(dv * (acc[k] + f[k]) + bb[k], 0.0f);
        if (lane == 0) ib[wid] = batch[node];
    }
    __syncthreads();
    // run-length reduce the 8 node rows by graph id (batch is sorted)
    int tf = threadIdx.x;
    if (tf < 128) {
        float run = hrow[0][tf];
        int cg = ib[0];
        for (int w = 1; w < 8; ++w) {
            int gg = ib[w];
            if (gg != cg) {
                atomicAdd(&PS[(size_t)cg * 128 + tf], run);
                run = hrow[w][tf];
                cg = gg;
            } else {
                run += hrow[w][tf];
            }
        }
        atomicAdd(&PS[(size_t)cg * 128 + tf], run);
    }
}

// ---------------- FC from pooled sums: out = (PS[g]/cnt) @ Wfc + bfc ----------------
__global__ __launch_bounds__(128) void fc_kernel(const float* __restrict__ PS,
                                                 const int* __restrict__ batch,
                                                 const float* __restrict__ Wfc,
                                                 const float* __restrict__ bfc,
                                                 float* __restrict__ OUT, int n) {
    int g = blockIdx.x;
    __shared__ int se[2];
    __shared__ float pooled[128];
    if (threadIdx.x < 2) {
        int target = g + threadIdx.x;
        int lo = 0, hi = n;
        while (lo < hi) {
            int mid = (lo + hi) >> 1;
            if (batch[mid] < target) lo = mid + 1; else hi = mid;
        }
        se[threadIdx.x] = lo;
    }
    __syncthreads();
    float cntf = (float)max(se[1] - se[0], 1);
    pooled[threadIdx.x] = PS[(size_t)g * 128 + threadIdx.x] / cntf;
    __syncthreads();
    if (threadIdx.x < 10) {
        float o = bfc[threadIdx.x];
        for (int k = 0; k < 128; ++k) o += pooled[k] * Wfc[k * 10 + threadIdx.x];
        OUT[g * 10 + threadIdx.x] = o;
    }
}

extern "C" void kernel_launch(void* const* d_in, const int* in_sizes, int n_in,
                              void* d_out, int out_size, void* d_ws, size_t ws_size,
                              hipStream_t stream) {
    const int N = N_NODES, E = N_EDGES, G = N_GRAPHS;
    const float* x = (const float*)d_in[0];
    const int* ei = (const int*)d_in[1];
    const int* batch = (const int*)d_in[2];
    const float* W1 = (const float*)d_in[3];
    const float* b1 = (const float*)d_in[4];
    const float* W2 = (const float*)d_in[5];
    const float* b2 = (const float*)d_in[6];
    const float* W3 = (const float*)d_in[7];
    const float* b3 = (const float*)d_in[8];
    const float* Wfc = (const float*)d_in[9];
    const float* bfc = (const float*)d_in[10];
    const int* src = ei;
    const int* dst = ei + E;

    char* ws = (char*)d_ws;
    size_t off = 0;
    auto alloc = [&](size_t bytes) {
        void* p = ws + off;
        off = (off + bytes + 255) & ~(size_t)255;
        return p;
    };
    float* dinv = (float*)alloc((size_t)N * 4);
    int* rowptr = (int*)alloc((size_t)(N + 1) * 4);
    int* bhist = (int*)alloc((size_t)NBUK * 4);
    int* boff = (int*)alloc((size_t)(NBUK + 1) * 4);
    int* bcursor = (int*)alloc((size_t)NBUK * 4);
    int* esrc = (int*)alloc((size_t)E * 4);
    u16* W1t = (u16*)alloc((size_t)64 * 128 * 2);
    u16* W2t = (u16*)alloc((size_t)128 * 64 * 2);
    u16* W3t = (u16*)alloc((size_t)128 * 128 * 2);
    u16* TS1 = (u16*)alloc((size_t)N * 64 * 2);      // bf16 [N][64]
    u16* H1S = (u16*)alloc((size_t)N * 64 * 2);      // bf16 [N][64], pre-scaled
    u16* G2 = (u16*)alloc((size_t)N * 64 * 2);       // bf16 [N][64]
    u16* H2S = (u16*)alloc((size_t)N * 128 * 2);     // bf16 [N][128], pre-scaled
    u16* TS3 = (u16*)alloc((size_t)N * 128 * 2);     // bf16 [N][128]
    float* PS = (float*)alloc((size_t)G * 128 * 4);  // pooled sums [1024][128]
    int* sorted = (int*)TS3;  // packed edges during preproc; TS3 written later

    // ---- graph preprocessing: bucket-sorted CSR build ----
    hipMemsetAsync(bhist, 0, (size_t)NBUK * 4, stream);
    hipMemsetAsync(PS, 0, (size_t)G * 128 * 4, stream);
    bhist_kernel<<<128, 256, 0, stream>>>(dst, bhist, E);
    bscan_kernel<<<1, 256, 0, stream>>>(bhist, boff, bcursor);
    const int NTILES = (E + SCAT_TILE - 1) / SCAT_TILE;
    bucket_scatter_kernel<<<NTILES, 256, 0, stream>>>(src, dst, bcursor, sorted, E);
    bucket_build_kernel<<<NBUK, 256, 0, stream>>>(sorted, boff, rowptr, dinv, esrc, N);

    // ---- weight conversion (all three, one kernel) ----
    convw_all_kernel<<<128, 256, 0, stream>>>(W1, W2, W3, W1t, W2t, W3t);

    const int GEMM_GRID = (N + 255) / 256;
    const int AGG_GRID = (N + 3) / 4;
    // ---- layer 1: 128 -> 64 ----
    mfma_gemm_kernel<128, 64, 0, 1><<<GEMM_GRID, 256, 0, stream>>>(x, W1t, nullptr, dinv,
                                                                   TS1, N);
    pull_agg_w_kernel<64, 1, 1><<<AGG_GRID, 256, 0, stream>>>((const uint4*)TS1, rowptr,
                                                              esrc, dinv, b1, H1S, N);
    // ---- layer 2: 64 -> 128 ----
    pull_agg_w_kernel<64, 1, 2><<<AGG_GRID, 256, 0, stream>>>((const uint4*)H1S, rowptr,
                                                              esrc, dinv, nullptr, G2, N);
    mfma_gemm_kernel<64, 128, 1, 0><<<GEMM_GRID, 256, 0, stream>>>(G2, W2t, b2, dinv,
                                                                   H2S, N);
    // ---- layer 3: 128 -> 128, aggregation fused with mean-pool partials ----
    mfma_gemm_kernel<128, 128, 0, 0><<<GEMM_GRID, 256, 0, stream>>>(H2S, W3t, nullptr, dinv,
                                                                    TS3, N);
    pull_agg_pool_kernel<<<N / 8, 512, 0, stream>>>((const uint4*)TS3, rowptr, esrc,
                                                    dinv, b3, batch, PS, N);
    // ---- FC from pooled sums ----
    fc_kernel<<<G, 128, 0, stream>>>(PS, batch, Wfc, bfc, (float*)d_out, N);
}

// Round 9
// 270.201 us; speedup vs baseline: 1.1880x; 1.1035x over previous
//
#include <hip/hip_runtime.h>
#include <hip/hip_bf16.h>

typedef unsigned int u32;
typedef unsigned short u16;
typedef __attribute__((ext_vector_type(8))) short short8;
typedef __attribute__((ext_vector_type(4))) float f32x4;

#define N_NODES 100000
#define N_EDGES 1600000
#define N_GRAPHS 1024
#define BUK_SHIFT 7         // 128 nodes per bucket
#define NBUK 782            // ceil(100000 / 128)
#define BUK_CAP 2560        // mean fill 2046, sd ~45 -> +11 sigma headroom
#define SCAT_EPT 16         // edges per thread in bucket_scatter
#define SCAT_TILE (256 * SCAT_EPT)

// ---- bf16 helpers (RNE) ----
__device__ __forceinline__ float bflo(u32 u) { return __uint_as_float(u << 16); }
__device__ __forceinline__ float bfhi(u32 u) { return __uint_as_float(u & 0xFFFF0000u); }
__device__ __forceinline__ u32 bf1(float a) {
    u32 ua = __float_as_uint(a);
    ua += 0x7FFF + ((ua >> 16) & 1);
    return ua >> 16;
}
__device__ __forceinline__ u32 bfpack(float a, float b) {
    u32 ua = __float_as_uint(a);
    u32 ub = __float_as_uint(b);
    ua += 0x7FFF + ((ua >> 16) & 1);
    ub += 0x7FFF + ((ub >> 16) & 1);
    return (ua >> 16) | (ub & 0xFFFF0000u);
}
__device__ __forceinline__ void unpack8(uint4 v, float* f) {
    f[0] = bflo(v.x); f[1] = bfhi(v.x); f[2] = bflo(v.y); f[3] = bfhi(v.y);
    f[4] = bflo(v.z); f[5] = bfhi(v.z); f[6] = bflo(v.w); f[7] = bfhi(v.w);
}

// ---- setup kernel: W transposes->bf16, zero PS, init gapped bucket cursors ----
__global__ __launch_bounds__(256) void setup_kernel(const float* __restrict__ W1,
                                                    const float* __restrict__ W2,
                                                    const float* __restrict__ W3,
                                                    u16* __restrict__ W1t,
                                                    u16* __restrict__ W2t,
                                                    u16* __restrict__ W3t,
                                                    float* __restrict__ PS,
                                                    int* __restrict__ bcursor) {
    int i = blockIdx.x * 256 + threadIdx.x;
    if (i < 8192) {                 // W1: [128][64] -> W1t [64][128]
        int n = i / 128, k = i % 128;
        W1t[i] = (u16)bf1(W1[(size_t)k * 64 + n]);
    } else if (i < 16384) {         // W2: [64][128] -> W2t [128][64]
        int j = i - 8192;
        int n = j / 64, k = j % 64;
        W2t[j] = (u16)bf1(W2[(size_t)k * 128 + n]);
    } else if (i < 32768) {         // W3: [128][128] -> W3t [128][128]
        int j = i - 16384;
        int n = j / 128, k = j % 128;
        W3t[j] = (u16)bf1(W3[(size_t)k * 128 + n]);
    } else if (i < 40960) {         // zero PS: 8192 threads x 16 floats = 131072
        int j = i - 32768;
        float4 z = make_float4(0.f, 0.f, 0.f, 0.f);
        float4* p = (float4*)(PS + (size_t)j * 16);
        p[0] = z; p[1] = z; p[2] = z; p[3] = z;
    } else if (i < 40960 + NBUK) {  // gapped bucket cursors
        int b = i - 40960;
        bcursor[b] = b * BUK_CAP;
    }
}

// ---------------- scatter edges into gapped bucket order (packed) ----------------
__global__ __launch_bounds__(256) void bucket_scatter_kernel(const int* __restrict__ src,
                                                             const int* __restrict__ dst,
                                                             int* __restrict__ bcursor,
                                                             int* __restrict__ sorted, int E) {
    __shared__ int lhist[NBUK];
    __shared__ int lbase[NBUK];
    for (int i = threadIdx.x; i < NBUK; i += 256) lhist[i] = 0;
    __syncthreads();
    int base_i = blockIdx.x * SCAT_TILE;
    int s[SCAT_EPT], d[SCAT_EPT], lp[SCAT_EPT];
#pragma unroll
    for (int k = 0; k < SCAT_EPT; ++k) {
        int i = base_i + k * 256 + threadIdx.x;
        if (i < E) {
            s[k] = src[i];
            d[k] = dst[i];
            lp[k] = atomicAdd(&lhist[d[k] >> BUK_SHIFT], 1);
        }
    }
    __syncthreads();
    for (int b = threadIdx.x; b < NBUK; b += 256) {
        int c = lhist[b];
        lbase[b] = c ? atomicAdd(&bcursor[b], c) : 0;
    }
    __syncthreads();
#pragma unroll
    for (int k = 0; k < SCAT_EPT; ++k) {
        int i = base_i + k * 256 + threadIdx.x;
        if (i < E) {
            int b = d[k] >> BUK_SHIFT;
            sorted[lbase[b] + lp[k]] = (s[k] << BUK_SHIFT) | (d[k] & 127);
        }
    }
}

// ---- fused: per-bucket count + dinv + rowse(start,end) + gapped CSR fill ----
__global__ __launch_bounds__(256) void bucket_build_kernel(const int* __restrict__ sorted,
                                                           const int* __restrict__ bcursor,
                                                           int2* __restrict__ rowse,
                                                           float* __restrict__ dinv,
                                                           int* __restrict__ esrc, int n) {
    __shared__ int ncnt[128];
    __shared__ int sc[128];
    __shared__ int lbase[128];
    __shared__ int lcur[128];
    int tid = threadIdx.x;
    int b = blockIdx.x;
    int start = b * BUK_CAP;
    int end = bcursor[b];            // final cursor = start + bucket count
    if (tid < 128) ncnt[tid] = 0;
    __syncthreads();
    for (int j = start + tid; j < end; j += 256)
        atomicAdd(&ncnt[sorted[j] & 127], 1);
    __syncthreads();
    if (tid < 128) sc[tid] = ncnt[tid];
    __syncthreads();
    for (int off = 1; off < 128; off <<= 1) {
        int v = 0;
        if (tid < 128 && tid >= off) v = sc[tid - off];
        __syncthreads();
        if (tid < 128) sc[tid] += v;
        __syncthreads();
    }
    if (tid < 128) {
        int excl = sc[tid] - ncnt[tid];
        int pos = start + excl;
        lbase[tid] = pos;
        lcur[tid] = 0;
        int node = (b << BUK_SHIFT) + tid;
        if (node < n) {
            rowse[node] = make_int2(pos, pos + ncnt[tid]);
            dinv[node] = rsqrtf((float)ncnt[tid] + 1.0f);
        }
    }
    __syncthreads();
    for (int j = start + tid; j < end; j += 256) {
        int p = sorted[j];
        int ln = p & 127;
        int off = atomicAdd(&lcur[ln], 1);
        esrc[lbase[ln] + off] = p >> BUK_SHIFT;
    }
}

// ---------------- MFMA GEMM: C[M][NOUT] bf16 = A[M][K] @ Wt^T ----------------
// 2 sub-tiles (32 rows) per wave, grid = ceil(M/128) for occupancy.
template <int K, int NOUT, int EPI, int A_F32>
__global__ __launch_bounds__(256) void mfma_gemm_kernel(const void* __restrict__ Aptr,
                                                        const u16* __restrict__ Wt,
                                                        const float* __restrict__ bias,
                                                        const float* __restrict__ dinv,
                                                        u16* __restrict__ C, int M) {
    constexpr int KP = K + 8;
    constexpr int NK = K / 32;
    constexpr int NCT = NOUT / 16;
    constexpr int SUBS = 2;
    __shared__ u16 wlds[NOUT * KP];
    int tid = threadIdx.x;
    constexpr int TOT = NOUT * K / 8;
    const uint4* wt4 = (const uint4*)Wt;
    for (int i = tid; i < TOT; i += 256) {
        int r = i / (K / 8), kc = i % (K / 8);
        *(uint4*)&wlds[r * KP + kc * 8] = wt4[i];
    }
    __syncthreads();

    int lane = tid & 63;
    int w = tid >> 6;
    int row0 = blockIdx.x * 128 + w * 32;

    short8 afr[SUBS][NK];
#pragma unroll
    for (int sub = 0; sub < SUBS; ++sub) {
        int arow = row0 + sub * 16 + (lane & 15);
        arow = min(arow, M - 1);
        if (A_F32) {
            const float* Af = (const float*)Aptr;
            float dv = dinv[arow];
#pragma unroll
            for (int ks = 0; ks < NK; ++ks) {
                int k0 = ks * 32 + (lane >> 4) * 8;
                const float4* p = (const float4*)(Af + (size_t)arow * K + k0);
                float4 uu = p[0], vv = p[1];
                uint4 q;
                q.x = bfpack(dv * uu.x, dv * uu.y);
                q.y = bfpack(dv * uu.z, dv * uu.w);
                q.z = bfpack(dv * vv.x, dv * vv.y);
                q.w = bfpack(dv * vv.z, dv * vv.w);
                afr[sub][ks] = *(short8*)&q;
            }
        } else {
            const u16* Ab = (const u16*)Aptr;
#pragma unroll
            for (int ks = 0; ks < NK; ++ks) {
                int k0 = ks * 32 + (lane >> 4) * 8;
                afr[sub][ks] = *(const short8*)(Ab + (size_t)arow * K + k0);
            }
        }
    }

    for (int ct = 0; ct < NCT; ++ct) {
        int bcol = ct * 16 + (lane & 15);
        short8 bfr[NK];
#pragma unroll
        for (int ks = 0; ks < NK; ++ks) {
            int k0 = ks * 32 + (lane >> 4) * 8;
            bfr[ks] = *(const short8*)&wlds[bcol * KP + k0];
        }
        float bc = 0.0f;
        if (EPI == 1) bc = bias[bcol];
#pragma unroll
        for (int sub = 0; sub < SUBS; ++sub) {
            f32x4 acc = {0.0f, 0.0f, 0.0f, 0.0f};
#pragma unroll
            for (int ks = 0; ks < NK; ++ks)
                acc = __builtin_amdgcn_mfma_f32_16x16x32_bf16(afr[sub][ks], bfr[ks], acc,
                                                              0, 0, 0);
            int rbase = row0 + sub * 16 + (lane >> 4) * 4;
            if (rbase < M) {    // rbase%4==0 && M%4==0 -> all 4 rows valid
                if (EPI == 0) {
#pragma unroll
                    for (int j = 0; j < 4; ++j)
                        C[(size_t)(rbase + j) * NOUT + bcol] = (u16)bf1(acc[j]);
                } else {
                    float4 dv4 = *(const float4*)(dinv + rbase);
                    float dvv[4] = {dv4.x, dv4.y, dv4.z, dv4.w};
#pragma unroll
                    for (int j = 0; j < 4; ++j) {
                        float o = dvv[j] * fmaxf(acc[j] + bc, 0.0f);
                        C[(size_t)(rbase + j) * NOUT + bcol] = (u16)bf1(o);
                    }
                }
            }
        }
    }
}

// ---- edge-parallel wave aggregation (F=64 layers) ----
// EPI=1: out = dv * relu(dv*acc + bias)     (agg1 -> pre-scaled h1')
// EPI=2: out = dv * acc                     (pre-agg2 on pre-scaled h1')
template <int F, int OUT_BF, int EPI>
__global__ __launch_bounds__(256) void pull_agg_w_kernel(const uint4* __restrict__ TS,
                                                         const int2* __restrict__ rowse,
                                                         const int* __restrict__ esrc,
                                                         const float* __restrict__ dinv,
                                                         const float* __restrict__ bias,
                                                         void* __restrict__ OUT, int n) {
    constexpr int TPN = F / 8;
    constexpr int EPG = 64 / TPN;
    int wid = threadIdx.x >> 6;
    int lane = threadIdx.x & 63;
    int node = blockIdx.x * 4 + wid;
    if (node >= n) return;
    int t = lane % TPN;
    int g = lane / TPN;
    float acc[8] = {0, 0, 0, 0, 0, 0, 0, 0};
    float f[8];
    int2 se = rowse[node];
    for (int j = se.x + g; j < se.y; j += EPG) {
        int s = esrc[j];
        unpack8(TS[(size_t)s * TPN + t], f);
#pragma unroll
        for (int k = 0; k < 8; ++k) acc[k] += f[k];
    }
#pragma unroll
    for (int k = 0; k < 8; ++k) {
#pragma unroll
        for (int m = TPN; m < 64; m <<= 1) acc[k] += __shfl_xor(acc[k], m, 64);
    }
    if (g == 0) {
        unpack8(TS[(size_t)node * TPN + t], f);
#pragma unroll
        for (int k = 0; k < 8; ++k) acc[k] += f[k];
        float dv = dinv[node];
        float o[8];
        if (EPI == 2) {
#pragma unroll
            for (int k = 0; k < 8; ++k) o[k] = dv * acc[k];
        } else {
            const float4* bias4 = (const float4*)bias;
            float4 b0 = bias4[t * 2], b1v = bias4[t * 2 + 1];
            float bb[8] = {b0.x, b0.y, b0.z, b0.w, b1v.x, b1v.y, b1v.z, b1v.w};
#pragma unroll
            for (int k = 0; k < 8; ++k) o[k] = fmaxf(dv * acc[k] + bb[k], 0.0f);
            if (EPI == 1) {
#pragma unroll
                for (int k = 0; k < 8; ++k) o[k] *= dv;
            }
        }
        if (OUT_BF) {
            uint4 pv;
            pv.x = bfpack(o[0], o[1]); pv.y = bfpack(o[2], o[3]);
            pv.z = bfpack(o[4], o[5]); pv.w = bfpack(o[6], o[7]);
            ((uint4*)OUT)[(size_t)node * TPN + t] = pv;
        } else {
            float4* O4 = (float4*)OUT;
            O4[(size_t)node * (F / 4) + t * 2] = make_float4(o[0], o[1], o[2], o[3]);
            O4[(size_t)node * (F / 4) + t * 2 + 1] = make_float4(o[4], o[5], o[6], o[7]);
        }
    }
}

// ---- fused layer-3 aggregation + mean-pool partial sums ----
// 4 waves/block (256 thr), one node per wave, grid = n/4 EXACT (no early return).
__global__ __launch_bounds__(256) void pull_agg_pool_kernel(const uint4* __restrict__ TS,
                                                            const int2* __restrict__ rowse,
                                                            const int* __restrict__ esrc,
                                                            const float* __restrict__ dinv,
                                                            const float* __restrict__ bias,
                                                            const int* __restrict__ batch,
                                                            float* __restrict__ PS, int n) {
    constexpr int TPN = 16;   // F=128: 16 lanes x 8 feats
    constexpr int EPG = 4;
    __shared__ float hrow[4][128];
    __shared__ int ib[4];
    int wid = threadIdx.x >> 6;
    int lane = threadIdx.x & 63;
    int node = blockIdx.x * 4 + wid;   // always < n (grid exact)
    int t = lane % TPN;
    int g = lane / TPN;
    float acc[8] = {0, 0, 0, 0, 0, 0, 0, 0};
    float f[8];
    int2 se = rowse[node];
    for (int j = se.x + g; j < se.y; j += EPG) {
        int s = esrc[j];
        unpack8(TS[(size_t)s * TPN + t], f);
#pragma unroll
        for (int k = 0; k < 8; ++k) acc[k] += f[k];
    }
#pragma unroll
    for (int k = 0; k < 8; ++k) {
#pragma unroll
        for (int m = TPN; m < 64; m <<= 1) acc[k] += __shfl_xor(acc[k], m, 64);
    }
    if (g == 0) {
        unpack8(TS[(size_t)node * TPN + t], f);
        float dv = dinv[node];
        const float4* bias4 = (const float4*)bias;
        float4 b0 = bias4[t * 2], b1v = bias4[t * 2 + 1];
        float bb[8] = {b0.x, b0.y, b0.z, b0.w, b1v.x, b1v.y, b1v.z, b1v.w};
#pragma unroll
        for (int k = 0; k < 8; ++k)
            hrow[wid][t * 8 + k] = fmaxf(dv * (acc[k] + f[k]) + bb[k], 0.0f);
        if (lane == 0) ib[wid] = batch[node];
    }
    __syncthreads();
    // run-length reduce 4 node rows by graph id (batch sorted)
    int tf = threadIdx.x;
    if (tf < 128) {
        float run = hrow[0][tf];
        int cg = ib[0];
        for (int w = 1; w < 4; ++w) {
            int gg = ib[w];
            if (gg != cg) {
                atomicAdd(&PS[(size_t)cg * 128 + tf], run);
                run = hrow[w][tf];
                cg = gg;
            } else {
                run += hrow[w][tf];
            }
        }
        atomicAdd(&PS[(size_t)cg * 128 + tf], run);
    }
}

// ---------------- FC from pooled sums: out = (PS[g]/cnt) @ Wfc + bfc ----------------
__global__ __launch_bounds__(128) void fc_kernel(const float* __restrict__ PS,
                                                 const int* __restrict__ batch,
                                                 const float* __restrict__ Wfc,
                                                 const float* __restrict__ bfc,
                                                 float* __restrict__ OUT, int n) {
    int g = blockIdx.x;
    __shared__ int se[2];
    __shared__ float pooled[128];
    if (threadIdx.x < 2) {
        int target = g + threadIdx.x;
        int lo = 0, hi = n;
        while (lo < hi) {
            int mid = (lo + hi) >> 1;
            if (batch[mid] < target) lo = mid + 1; else hi = mid;
        }
        se[threadIdx.x] = lo;
    }
    __syncthreads();
    float cntf = (float)max(se[1] - se[0], 1);
    pooled[threadIdx.x] = PS[(size_t)g * 128 + threadIdx.x] / cntf;
    __syncthreads();
    if (threadIdx.x < 10) {
        float o = bfc[threadIdx.x];
        for (int k = 0; k < 128; ++k) o += pooled[k] * Wfc[k * 10 + threadIdx.x];
        OUT[g * 10 + threadIdx.x] = o;
    }
}

extern "C" void kernel_launch(void* const* d_in, const int* in_sizes, int n_in,
                              void* d_out, int out_size, void* d_ws, size_t ws_size,
                              hipStream_t stream) {
    const int N = N_NODES, E = N_EDGES, G = N_GRAPHS;
    const float* x = (const float*)d_in[0];
    const int* ei = (const int*)d_in[1];
    const int* batch = (const int*)d_in[2];
    const float* W1 = (const float*)d_in[3];
    const float* b1 = (const float*)d_in[4];
    const float* W2 = (const float*)d_in[5];
    const float* b2 = (const float*)d_in[6];
    const float* W3 = (const float*)d_in[7];
    const float* b3 = (const float*)d_in[8];
    const float* Wfc = (const float*)d_in[9];
    const float* bfc = (const float*)d_in[10];
    const int* src = ei;
    const int* dst = ei + E;

    char* ws = (char*)d_ws;
    size_t off = 0;
    auto alloc = [&](size_t bytes) {
        void* p = ws + off;
        off = (off + bytes + 255) & ~(size_t)255;
        return p;
    };
    float* dinv = (float*)alloc((size_t)N * 4);
    int2* rowse = (int2*)alloc((size_t)N * 8);
    int* bcursor = (int*)alloc((size_t)NBUK * 4);
    int* esrc = (int*)alloc((size_t)NBUK * BUK_CAP * 4);   // gapped, ~8 MB
    u16* W1t = (u16*)alloc((size_t)64 * 128 * 2);
    u16* W2t = (u16*)alloc((size_t)128 * 64 * 2);
    u16* W3t = (u16*)alloc((size_t)128 * 128 * 2);
    u16* TS1 = (u16*)alloc((size_t)N * 64 * 2);      // bf16 [N][64]
    u16* H1S = (u16*)alloc((size_t)N * 64 * 2);      // bf16 [N][64], pre-scaled
    u16* G2 = (u16*)alloc((size_t)N * 64 * 2);       // bf16 [N][64]
    u16* H2S = (u16*)alloc((size_t)N * 128 * 2);     // bf16 [N][128], pre-scaled
    u16* TS3 = (u16*)alloc((size_t)N * 128 * 2);     // bf16 [N][128]
    float* PS = (float*)alloc((size_t)G * 128 * 4);  // pooled sums
    int* sorted = (int*)TS3;  // gapped packed edges (8 MB) alias TS3 (25.6 MB)

    // ---- setup: W conversion + PS zero + cursor init (one kernel, no memsets) ----
    setup_kernel<<<164, 256, 0, stream>>>(W1, W2, W3, W1t, W2t, W3t, PS, bcursor);
    // ---- graph preprocessing: gapped bucket sort + CSR build ----
    const int NTILES = (E + SCAT_TILE - 1) / SCAT_TILE;
    bucket_scatter_kernel<<<NTILES, 256, 0, stream>>>(src, dst, bcursor, sorted, E);
    bucket_build_kernel<<<NBUK, 256, 0, stream>>>(sorted, bcursor, rowse, dinv, esrc, N);

    const int GEMM_GRID = (N + 127) / 128;   // 782
    const int AGG_GRID = N / 4;              // 25000 (N%4==0)
    // ---- layer 1: 128 -> 64 ----
    mfma_gemm_kernel<128, 64, 0, 1><<<GEMM_GRID, 256, 0, stream>>>(x, W1t, nullptr, dinv,
                                                                   TS1, N);
    pull_agg_w_kernel<64, 1, 1><<<AGG_GRID, 256, 0, stream>>>((const uint4*)TS1, rowse,
                                                              esrc, dinv, b1, H1S, N);
    // ---- layer 2: 64 -> 128 ----
    pull_agg_w_kernel<64, 1, 2><<<AGG_GRID, 256, 0, stream>>>((const uint4*)H1S, rowse,
                                                              esrc, dinv, nullptr, G2, N);
    mfma_gemm_kernel<64, 128, 1, 0><<<GEMM_GRID, 256, 0, stream>>>(G2, W2t, b2, dinv,
                                                                   H2S, N);
    // ---- layer 3: 128 -> 128, aggregation fused with mean-pool partials ----
    mfma_gemm_kernel<128, 128, 0, 0><<<GEMM_GRID, 256, 0, stream>>>(H2S, W3t, nullptr, dinv,
                                                                    TS3, N);
    pull_agg_pool_kernel<<<AGG_GRID, 256, 0, stream>>>((const uint4*)TS3, rowse, esrc,
                                                       dinv, b3, batch, PS, N);
    // ---- FC from pooled sums ----
    fc_kernel<<<G, 128, 0, stream>>>(PS, batch, Wfc, bfc, (float*)d_out, N);
}